// Round 10
// baseline (470.008 us; speedup 1.0000x reference)
//
#include <hip/hip_runtime.h>
#include <math.h>

#define T_STEPS 8192
#define GROUP   32
#define NG      (T_STEPS / GROUP)   // 256 groups

// hardware transcendentals (v_exp_f32 = 2^x, v_log_f32 = log2 x)
__device__ __forceinline__ float hw_exp2(float x) { return __builtin_amdgcn_exp2f(x); }
__device__ __forceinline__ float hw_log2(float x) { return __builtin_amdgcn_logf(x); }

// ---------------------------------------------------------------------------
// 4-wave specialized pipeline. 16 blocks x 256 threads (4 waves, 1/SIMD).
//   wave0 (A):  snow bucket -> infl, acmax*infl, 1-(pet+ki)/s1max
//   wave1 (B):  s1 recurrence -> af*perc, af*(qsurf+qif)     [2 trans chain]
//   wave2 (C1): band sums via transposed serial adds (no cross-lane ops)
//   wave3 (C2): s2 recurrence + q                            [2 trans chain]
// Stages hand off 32-step groups through double-buffered LDS, one barrier
// per iteration. R9 post-mortem: DPP reduction issue (16 ops/step + hazards)
// was the bottleneck stage; serial-add reduction on a spare wave is ~4x
// cheaper and the two transcendental chains (B, C2) become the floor.
// ---------------------------------------------------------------------------
__global__ __launch_bounds__(256, 1) void fuse_pipe_kernel(
    const float* __restrict__ raw,        // [64][29]
    const float* __restrict__ forcing,    // [8192][3]
    const float* __restrict__ state_init, // [2]
    const float* __restrict__ area_frac,  // [16]
    const float* __restrict__ mean_elev,  // [16]
    float* __restrict__ qout)             // d_out: [64][8192]
{
    const int tid  = threadIdx.x;
    const int wid  = tid >> 6;      // 0..3
    const int lane = tid & 63;
    const int grp  = lane >> 4;     // ensemble within wave
    const int nb   = lane & 15;     // band
    const int e    = blockIdx.x * 4 + grp;

    // A -> B (row = 64 floats, write/read both lane-linear: conflict-free)
    __shared__ float bufI[2][GROUP][64];
    __shared__ float bufA[2][GROUP][64];
    __shared__ float bufC[2][GROUP][64];
    // B -> C1 (row padded to 68: C1 reads 16-consecutive runs per lane;
    // 64-float rows would put every step on the same bank set -> 16-way)
    __shared__ __align__(16) float bufP[2][GROUP][68];
    __shared__ __align__(16) float bufQ[2][GROUP][68];
    // C1 -> C2 (tiny; rows padded to 36 to stay 16B-aligned + bank-spread)
    __shared__ __align__(16) float bufR[2][4][36];   // rech sums [e][tt]
    __shared__ __align__(16) float bufS[2][4][36];   // surface-q sums

    const float* rp = raw + e * 29;
    auto phys = [&](int idx, float lo, float hi) {
        float x = rp[idx];
        float s = 1.0f / (1.0f + expf(-x));
        return lo + (hi - lo) * s;
    };
    const float s1max = phys(0,  50.0f,  5000.0f);
    const float s2max = phys(1,  100.0f, 10000.0f);
    const float ku    = phys(6,  0.01f,  1000.0f);
    const float c_exp = phys(7,  1.0f,   20.0f);
    const float ki    = phys(11, 0.01f,  1000.0f);
    const float ks    = phys(12, 0.001f, 10000.0f);
    const float n_exp = phys(13, 1.0f,   10.0f);
    const float acmax = phys(17, 0.05f,  0.95f);
    const float b_exp = phys(18, 0.001f, 3.0f);
    const float train = phys(22, -2.0f,  4.0f);
    const float tmelt = phys(23, -2.0f,  4.0f);
    const float mrate = phys(24, 1.0f,   10.0f);
    const float lapse = phys(25, -9.8f,  0.0f);
    const float opg   = phys(26, 0.0f,   1.0f);

    const float delev  = (mean_elev[nb] - 1500.0f) / 1000.0f;
    const float tshift = lapse * delev;
    const float pmult  = fmaxf(1.0f + opg * delev, 0.0f);
    const float af     = area_frac[nb];
    const float inv_s1max = 1.0f / s1max;
    const float inv_s2max = 1.0f / s2max;
    const float afku   = af * ku;

    float swe = 0.0f;
    float s1  = state_init[0];
    float s2  = state_init[1];

    float* __restrict__ out = qout + (size_t)e * T_STEPS;
    const float4* __restrict__ fvec = (const float4*)forcing;  // 24 float4/group

    for (int i = 0; i < NG + 3; ++i) {
        if (wid == 0) {
            // ---- stage A: snow bucket + precompute, group i ----
            if (i < NG) {
                const int pb_ = i & 1;
                float f[96];
                const int base = i * 24;
                #pragma unroll
                for (int j = 0; j < 24; ++j) {
                    const float4 L = fvec[base + j];
                    f[4*j+0] = L.x; f[4*j+1] = L.y; f[4*j+2] = L.z; f[4*j+3] = L.w;
                }
                #pragma unroll
                for (int tt = 0; tt < GROUP; ++tt) {
                    const float p    = f[3*tt + 0];
                    const float pet  = f[3*tt + 1];
                    const float tair = f[3*tt + 2];
                    const float tb   = tair + tshift;
                    const float pcp  = p * pmult;
                    const float snow = (tb > train) ? 0.0f : pcp;
                    const float ssn  = swe + snow;
                    const float mcap = mrate * fmaxf(tb - tmelt, 0.0f);
                    const float swen = fmaxf(ssn - mcap, 0.0f);
                    const float infl = pcp + swe - swen;        // rain + melt
                    swe = swen;
                    bufI[pb_][tt][lane] = infl;
                    bufA[pb_][tt][lane] = acmax * infl;
                    bufC[pb_][tt][lane] = fmaf(-(pet + ki), inv_s1max, 1.0f);
                }
            }
        } else if (wid == 1) {
            // ---- stage B: s1 recurrence, group i-1 ----
            const int g = i - 1;
            if (g >= 0 && g < NG) {
                const int pb_ = g & 1;
                float fi[GROUP], fa[GROUP], fc[GROUP];
                #pragma unroll
                for (int tt = 0; tt < GROUP; ++tt) {
                    fi[tt] = bufI[pb_][tt][lane];
                    fa[tt] = bufA[pb_][tt][lane];
                    fc[tt] = bufC[pb_][tt][lane];
                }
                #pragma unroll
                for (int tt = 0; tt < GROUP; ++tt)
                    asm volatile("" : "+v"(fi[tt]), "+v"(fa[tt]), "+v"(fc[tt]));

                #pragma unroll
                for (int tt = 0; tt < GROUP; ++tt) {
                    const float w1   = s1 * inv_s1max;          // in [0,1]
                    const float lg   = hw_log2(w1);             // log2(0)=-inf ok
                    const float pwb  = hw_exp2(b_exp * lg);     // w1^b
                    const float pwc  = hw_exp2(c_exp * lg);     // w1^c
                    const float pre  = fmaf(fc[tt], s1, fi[tt]);
                    const float qsx  = fa[tt] * pwb;
                    const float t1   = fmaf(-ku, pwc, pre);
                    const float s1n  = t1 - qsx;
                    const float sHi  = fminf(s1n, s1max);
                    const float over1 = s1n - sHi;
                    s1 = fmaxf(sHi, 0.0f);
                    const float qif  = ki * w1;
                    bufP[pb_][tt][lane] = afku * pwc;           // af*perc
                    bufQ[pb_][tt][lane] = af * ((qsx + over1) + qif);
                }
            }
        } else if (wid == 2) {
            // ---- stage C1: band sums (transposed serial adds), group i-2 ----
            const int g = i - 2;
            if (g >= 0 && g < NG) {
                const int pb_ = g & 1;
                const int se   = lane >> 4;     // ensemble this lane sums for
                const int tlo  = lane & 15;     // step low index
                #pragma unroll
                for (int j = 0; j < 2; ++j) {
                    const int tt = tlo + 16 * j;
                    const float4 p0 = *(const float4*)&bufP[pb_][tt][se*16 + 0];
                    const float4 p1 = *(const float4*)&bufP[pb_][tt][se*16 + 4];
                    const float4 p2 = *(const float4*)&bufP[pb_][tt][se*16 + 8];
                    const float4 p3 = *(const float4*)&bufP[pb_][tt][se*16 + 12];
                    const float4 q0 = *(const float4*)&bufQ[pb_][tt][se*16 + 0];
                    const float4 q1 = *(const float4*)&bufQ[pb_][tt][se*16 + 4];
                    const float4 q2 = *(const float4*)&bufQ[pb_][tt][se*16 + 8];
                    const float4 q3 = *(const float4*)&bufQ[pb_][tt][se*16 + 12];
                    const float sp = ((p0.x+p0.y)+(p0.z+p0.w))
                                   + ((p1.x+p1.y)+(p1.z+p1.w))
                                   + ((p2.x+p2.y)+(p2.z+p2.w))
                                   + ((p3.x+p3.y)+(p3.z+p3.w));
                    const float sq = ((q0.x+q0.y)+(q0.z+q0.w))
                                   + ((q1.x+q1.y)+(q1.z+q1.w))
                                   + ((q2.x+q2.y)+(q2.z+q2.w))
                                   + ((q3.x+q3.y)+(q3.z+q3.w));
                    bufR[pb_][se][tt] = sp;
                    bufS[pb_][se][tt] = sq;
                }
            }
        } else {
            // ---- stage C2: s2 recurrence + q, group i-3 ----
            const int g = i - 3;
            if (g >= 0) {
                const int pb_ = g & 1;
                // group-uniform float4 reads: every lane of ensemble-group grp
                // gets the same 4 floats (LDS broadcast), 8 reads per array
                float4 r4[8], s4[8];
                #pragma unroll
                for (int k = 0; k < 8; ++k) {
                    r4[k] = *(const float4*)&bufR[pb_][grp][4*k];
                    s4[k] = *(const float4*)&bufS[pb_][grp][4*k];
                }
                #pragma unroll
                for (int k = 0; k < 8; ++k)
                    asm volatile("" : "+v"(r4[k].x), "+v"(r4[k].y),
                                      "+v"(r4[k].z), "+v"(r4[k].w),
                                      "+v"(s4[k].x), "+v"(s4[k].y),
                                      "+v"(s4[k].z), "+v"(s4[k].w));

                float qk0 = 0.0f, qk1 = 0.0f;
                #pragma unroll
                for (int tt = 0; tt < GROUP; ++tt) {
                    const float rech = (&r4[tt >> 2].x)[tt & 3];
                    const float qsum = (&s4[tt >> 2].x)[tt & 3];
                    const float w2r = s2 * inv_s2max;
                    const float lg2 = hw_log2(w2r);              // log2(0)=-inf ok
                    const float pw  = hw_exp2(n_exp * lg2);      // w2r^n
                    const float pwm = fminf(pw, 1.0f);           // == clip(w2r)^n
                    const float qb  = ks * pwm;
                    const float s2n = fmaf(-ks, pwm, s2 + rech);
                    const float sHi = fminf(s2n, s2max);
                    const float over2 = s2n - sHi;
                    s2 = fmaxf(sHi, 0.0f);
                    const float q = qsum + qb + over2;
                    if (tt < 16) qk0 = (tt == nb) ? q : qk0;
                    else         qk1 = ((tt - 16) == nb) ? q : qk1;
                }
                float* __restrict__ o = out + g * GROUP;
                o[nb]      = qk0;
                o[nb + 16] = qk1;
            }
        }
        __syncthreads();
    }
}

// ---------------------------------------------------------------------------
// Route: gamma unit-hydrograph, 30-tap causal FIR along time. In-place on
// d_out (full row staged in LDS before any write).
// ---------------------------------------------------------------------------
__global__ __launch_bounds__(256) void route_kernel(
    const float* __restrict__ raw,     // [64][29]
    float* __restrict__ q_io)          // d_out: in = q, out = routed
{
    __shared__ float w_sh[32];
    __shared__ float row[T_STEPS];     // 32 KB

    const int e   = blockIdx.x;
    const int tid = threadIdx.x;

    const float4* src  = (const float4*)(q_io + (size_t)e * T_STEPS);
    float4*       dst4 = (float4*)row;
    for (int i = tid; i < T_STEPS / 4; i += 256) dst4[i] = src[i];

    if (tid < 32) {
        float x     = raw[e * 29 + 21];                 // mu_t raw
        float sig   = 1.0f / (1.0f + expf(-x));
        float delay = 0.01f + (5.0f - 0.01f) * sig;
        float wv = 0.0f;
        if (tid < 30) {
            const float tm   = (float)tid + 0.5f;
            const float kk   = 2.5f;
            const float lgam = 0.28468287047291918f;    // lgamma(2.5)
            float lp = (kk - 1.0f) * logf(tm) - tm / delay - lgam - kk * logf(delay);
            wv = expf(lp);
        }
        w_sh[tid] = wv;
    }
    __syncthreads();
    if (tid == 0) {
        float s = 0.0f;
        for (int l = 0; l < 30; ++l) s += w_sh[l];
        w_sh[31] = 1.0f / s;
    }
    __syncthreads();

    float wloc[30];
    const float inv = w_sh[31];
    #pragma unroll
    for (int l = 0; l < 30; ++l) wloc[l] = w_sh[l] * inv;

    float* __restrict__ out = q_io + (size_t)e * T_STEPS;
    for (int t = tid; t < T_STEPS; t += 256) {
        float acc = 0.0f;
        #pragma unroll
        for (int l = 0; l < 30; ++l) {
            const int idx = t - l;
            const float v = (idx >= 0) ? row[idx] : 0.0f;
            acc = fmaf(wloc[l], v, acc);
        }
        out[t] = acc;
    }
}

// ---------------------------------------------------------------------------
extern "C" void kernel_launch(void* const* d_in, const int* in_sizes, int n_in,
                              void* d_out, int out_size, void* d_ws, size_t ws_size,
                              hipStream_t stream) {
    const float* raw        = (const float*)d_in[0];   // (64, 29)
    const float* forcing    = (const float*)d_in[1];   // (8192, 3)
    const float* state_init = (const float*)d_in[2];   // (2,)
    const float* area_frac  = (const float*)d_in[3];   // (16,)
    const float* mean_elev  = (const float*)d_in[4];   // (16,)

    float* out = (float*)d_out;                        // (64, 8192)

    fuse_pipe_kernel<<<16, 256, 0, stream>>>(raw, forcing, state_init,
                                             area_frac, mean_elev, out);
    route_kernel<<<64, 256, 0, stream>>>(raw, out);
}

// Round 11
// 469.973 us; speedup vs baseline: 1.0001x; 1.0001x over previous
//
#include <hip/hip_runtime.h>
#include <math.h>

#define T_STEPS 8192
#define GROUP   32
#define NG      (T_STEPS / GROUP)   // 256 groups

// hardware transcendentals (v_exp_f32 = 2^x, v_log_f32 = log2 x)
__device__ __forceinline__ float hw_exp2(float x) { return __builtin_amdgcn_exp2f(x); }
__device__ __forceinline__ float hw_log2(float x) { return __builtin_amdgcn_logf(x); }

// ---------------------------------------------------------------------------
// 4-wave specialized pipeline. 16 blocks x 256 threads (4 waves, 1/SIMD).
//   wave0 (A):  snow bucket -> infl, acmax*infl, 1-(pet+ki)/s1max
//   wave1 (B):  s1 recurrence -> af*perc, af*(qsurf+qif)     [2 trans chain]
//   wave2 (C1): band sums via transposed serial adds (no cross-lane ops)
//   wave3 (C2): s2 recurrence + q                            [2 trans chain]
// Stages hand off 32-step groups through double-buffered LDS, one barrier
// per iteration. R9 post-mortem: DPP reduction issue (16 ops/step + hazards)
// was the bottleneck stage; serial-add reduction on a spare wave is ~4x
// cheaper and the two transcendental chains (B, C2) become the floor.
// ---------------------------------------------------------------------------
__global__ __launch_bounds__(256, 1) void fuse_pipe_kernel(
    const float* __restrict__ raw,        // [64][29]
    const float* __restrict__ forcing,    // [8192][3]
    const float* __restrict__ state_init, // [2]
    const float* __restrict__ area_frac,  // [16]
    const float* __restrict__ mean_elev,  // [16]
    float* __restrict__ qout)             // d_out: [64][8192]
{
    const int tid  = threadIdx.x;
    const int wid  = tid >> 6;      // 0..3
    const int lane = tid & 63;
    const int grp  = lane >> 4;     // ensemble within wave
    const int nb   = lane & 15;     // band
    const int e    = blockIdx.x * 4 + grp;

    // A -> B (row = 64 floats, write/read both lane-linear: conflict-free)
    __shared__ float bufI[2][GROUP][64];
    __shared__ float bufA[2][GROUP][64];
    __shared__ float bufC[2][GROUP][64];
    // B -> C1 (row padded to 68: C1 reads 16-consecutive runs per lane;
    // 64-float rows would put every step on the same bank set -> 16-way)
    __shared__ __align__(16) float bufP[2][GROUP][68];
    __shared__ __align__(16) float bufQ[2][GROUP][68];
    // C1 -> C2 (tiny; rows padded to 36 to stay 16B-aligned + bank-spread)
    __shared__ __align__(16) float bufR[2][4][36];   // rech sums [e][tt]
    __shared__ __align__(16) float bufS[2][4][36];   // surface-q sums

    const float* rp = raw + e * 29;
    auto phys = [&](int idx, float lo, float hi) {
        float x = rp[idx];
        float s = 1.0f / (1.0f + expf(-x));
        return lo + (hi - lo) * s;
    };
    const float s1max = phys(0,  50.0f,  5000.0f);
    const float s2max = phys(1,  100.0f, 10000.0f);
    const float ku    = phys(6,  0.01f,  1000.0f);
    const float c_exp = phys(7,  1.0f,   20.0f);
    const float ki    = phys(11, 0.01f,  1000.0f);
    const float ks    = phys(12, 0.001f, 10000.0f);
    const float n_exp = phys(13, 1.0f,   10.0f);
    const float acmax = phys(17, 0.05f,  0.95f);
    const float b_exp = phys(18, 0.001f, 3.0f);
    const float train = phys(22, -2.0f,  4.0f);
    const float tmelt = phys(23, -2.0f,  4.0f);
    const float mrate = phys(24, 1.0f,   10.0f);
    const float lapse = phys(25, -9.8f,  0.0f);
    const float opg   = phys(26, 0.0f,   1.0f);

    const float delev  = (mean_elev[nb] - 1500.0f) / 1000.0f;
    const float tshift = lapse * delev;
    const float pmult  = fmaxf(1.0f + opg * delev, 0.0f);
    const float af     = area_frac[nb];
    const float inv_s1max = 1.0f / s1max;
    const float inv_s2max = 1.0f / s2max;
    const float afku   = af * ku;

    float swe = 0.0f;
    float s1  = state_init[0];
    float s2  = state_init[1];

    float* __restrict__ out = qout + (size_t)e * T_STEPS;
    const float4* __restrict__ fvec = (const float4*)forcing;  // 24 float4/group

    for (int i = 0; i < NG + 3; ++i) {
        if (wid == 0) {
            // ---- stage A: snow bucket + precompute, group i ----
            if (i < NG) {
                const int pb_ = i & 1;
                float f[96];
                const int base = i * 24;
                #pragma unroll
                for (int j = 0; j < 24; ++j) {
                    const float4 L = fvec[base + j];
                    f[4*j+0] = L.x; f[4*j+1] = L.y; f[4*j+2] = L.z; f[4*j+3] = L.w;
                }
                #pragma unroll
                for (int tt = 0; tt < GROUP; ++tt) {
                    const float p    = f[3*tt + 0];
                    const float pet  = f[3*tt + 1];
                    const float tair = f[3*tt + 2];
                    const float tb   = tair + tshift;
                    const float pcp  = p * pmult;
                    const float snow = (tb > train) ? 0.0f : pcp;
                    const float ssn  = swe + snow;
                    const float mcap = mrate * fmaxf(tb - tmelt, 0.0f);
                    const float swen = fmaxf(ssn - mcap, 0.0f);
                    const float infl = pcp + swe - swen;        // rain + melt
                    swe = swen;
                    bufI[pb_][tt][lane] = infl;
                    bufA[pb_][tt][lane] = acmax * infl;
                    bufC[pb_][tt][lane] = fmaf(-(pet + ki), inv_s1max, 1.0f);
                }
            }
        } else if (wid == 1) {
            // ---- stage B: s1 recurrence, group i-1 ----
            const int g = i - 1;
            if (g >= 0 && g < NG) {
                const int pb_ = g & 1;
                float fi[GROUP], fa[GROUP], fc[GROUP];
                #pragma unroll
                for (int tt = 0; tt < GROUP; ++tt) {
                    fi[tt] = bufI[pb_][tt][lane];
                    fa[tt] = bufA[pb_][tt][lane];
                    fc[tt] = bufC[pb_][tt][lane];
                }
                #pragma unroll
                for (int tt = 0; tt < GROUP; ++tt)
                    asm volatile("" : "+v"(fi[tt]), "+v"(fa[tt]), "+v"(fc[tt]));

                #pragma unroll
                for (int tt = 0; tt < GROUP; ++tt) {
                    const float w1   = s1 * inv_s1max;          // in [0,1]
                    const float lg   = hw_log2(w1);             // log2(0)=-inf ok
                    const float pwb  = hw_exp2(b_exp * lg);     // w1^b
                    const float pwc  = hw_exp2(c_exp * lg);     // w1^c
                    const float pre  = fmaf(fc[tt], s1, fi[tt]);
                    const float qsx  = fa[tt] * pwb;
                    const float t1   = fmaf(-ku, pwc, pre);
                    const float s1n  = t1 - qsx;
                    const float sHi  = fminf(s1n, s1max);
                    const float over1 = s1n - sHi;
                    s1 = fmaxf(sHi, 0.0f);
                    const float qif  = ki * w1;
                    bufP[pb_][tt][lane] = afku * pwc;           // af*perc
                    bufQ[pb_][tt][lane] = af * ((qsx + over1) + qif);
                }
            }
        } else if (wid == 2) {
            // ---- stage C1: band sums (transposed serial adds), group i-2 ----
            const int g = i - 2;
            if (g >= 0 && g < NG) {
                const int pb_ = g & 1;
                const int se   = lane >> 4;     // ensemble this lane sums for
                const int tlo  = lane & 15;     // step low index
                #pragma unroll
                for (int j = 0; j < 2; ++j) {
                    const int tt = tlo + 16 * j;
                    const float4 p0 = *(const float4*)&bufP[pb_][tt][se*16 + 0];
                    const float4 p1 = *(const float4*)&bufP[pb_][tt][se*16 + 4];
                    const float4 p2 = *(const float4*)&bufP[pb_][tt][se*16 + 8];
                    const float4 p3 = *(const float4*)&bufP[pb_][tt][se*16 + 12];
                    const float4 q0 = *(const float4*)&bufQ[pb_][tt][se*16 + 0];
                    const float4 q1 = *(const float4*)&bufQ[pb_][tt][se*16 + 4];
                    const float4 q2 = *(const float4*)&bufQ[pb_][tt][se*16 + 8];
                    const float4 q3 = *(const float4*)&bufQ[pb_][tt][se*16 + 12];
                    const float sp = ((p0.x+p0.y)+(p0.z+p0.w))
                                   + ((p1.x+p1.y)+(p1.z+p1.w))
                                   + ((p2.x+p2.y)+(p2.z+p2.w))
                                   + ((p3.x+p3.y)+(p3.z+p3.w));
                    const float sq = ((q0.x+q0.y)+(q0.z+q0.w))
                                   + ((q1.x+q1.y)+(q1.z+q1.w))
                                   + ((q2.x+q2.y)+(q2.z+q2.w))
                                   + ((q3.x+q3.y)+(q3.z+q3.w));
                    bufR[pb_][se][tt] = sp;
                    bufS[pb_][se][tt] = sq;
                }
            }
        } else {
            // ---- stage C2: s2 recurrence + q, group i-3 ----
            const int g = i - 3;
            if (g >= 0) {
                const int pb_ = g & 1;
                // group-uniform float4 reads: every lane of ensemble-group grp
                // gets the same 4 floats (LDS broadcast), 8 reads per array
                float4 r4[8], s4[8];
                #pragma unroll
                for (int k = 0; k < 8; ++k) {
                    r4[k] = *(const float4*)&bufR[pb_][grp][4*k];
                    s4[k] = *(const float4*)&bufS[pb_][grp][4*k];
                }
                #pragma unroll
                for (int k = 0; k < 8; ++k)
                    asm volatile("" : "+v"(r4[k].x), "+v"(r4[k].y),
                                      "+v"(r4[k].z), "+v"(r4[k].w),
                                      "+v"(s4[k].x), "+v"(s4[k].y),
                                      "+v"(s4[k].z), "+v"(s4[k].w));

                float qk0 = 0.0f, qk1 = 0.0f;
                #pragma unroll
                for (int tt = 0; tt < GROUP; ++tt) {
                    const float rech = (&r4[tt >> 2].x)[tt & 3];
                    const float qsum = (&s4[tt >> 2].x)[tt & 3];
                    const float w2r = s2 * inv_s2max;
                    const float lg2 = hw_log2(w2r);              // log2(0)=-inf ok
                    const float pw  = hw_exp2(n_exp * lg2);      // w2r^n
                    const float pwm = fminf(pw, 1.0f);           // == clip(w2r)^n
                    const float qb  = ks * pwm;
                    const float s2n = fmaf(-ks, pwm, s2 + rech);
                    const float sHi = fminf(s2n, s2max);
                    const float over2 = s2n - sHi;
                    s2 = fmaxf(sHi, 0.0f);
                    const float q = qsum + qb + over2;
                    if (tt < 16) qk0 = (tt == nb) ? q : qk0;
                    else         qk1 = ((tt - 16) == nb) ? q : qk1;
                }
                float* __restrict__ o = out + g * GROUP;
                o[nb]      = qk0;
                o[nb + 16] = qk1;
            }
        }
        __syncthreads();
    }
}

// ---------------------------------------------------------------------------
// Route: gamma unit-hydrograph, 30-tap causal FIR along time. In-place on
// d_out (full row staged in LDS before any write).
// ---------------------------------------------------------------------------
__global__ __launch_bounds__(256) void route_kernel(
    const float* __restrict__ raw,     // [64][29]
    float* __restrict__ q_io)          // d_out: in = q, out = routed
{
    __shared__ float w_sh[32];
    __shared__ float row[T_STEPS];     // 32 KB

    const int e   = blockIdx.x;
    const int tid = threadIdx.x;

    const float4* src  = (const float4*)(q_io + (size_t)e * T_STEPS);
    float4*       dst4 = (float4*)row;
    for (int i = tid; i < T_STEPS / 4; i += 256) dst4[i] = src[i];

    if (tid < 32) {
        float x     = raw[e * 29 + 21];                 // mu_t raw
        float sig   = 1.0f / (1.0f + expf(-x));
        float delay = 0.01f + (5.0f - 0.01f) * sig;
        float wv = 0.0f;
        if (tid < 30) {
            const float tm   = (float)tid + 0.5f;
            const float kk   = 2.5f;
            const float lgam = 0.28468287047291918f;    // lgamma(2.5)
            float lp = (kk - 1.0f) * logf(tm) - tm / delay - lgam - kk * logf(delay);
            wv = expf(lp);
        }
        w_sh[tid] = wv;
    }
    __syncthreads();
    if (tid == 0) {
        float s = 0.0f;
        for (int l = 0; l < 30; ++l) s += w_sh[l];
        w_sh[31] = 1.0f / s;
    }
    __syncthreads();

    float wloc[30];
    const float inv = w_sh[31];
    #pragma unroll
    for (int l = 0; l < 30; ++l) wloc[l] = w_sh[l] * inv;

    float* __restrict__ out = q_io + (size_t)e * T_STEPS;
    for (int t = tid; t < T_STEPS; t += 256) {
        float acc = 0.0f;
        #pragma unroll
        for (int l = 0; l < 30; ++l) {
            const int idx = t - l;
            const float v = (idx >= 0) ? row[idx] : 0.0f;
            acc = fmaf(wloc[l], v, acc);
        }
        out[t] = acc;
    }
}

// ---------------------------------------------------------------------------
extern "C" void kernel_launch(void* const* d_in, const int* in_sizes, int n_in,
                              void* d_out, int out_size, void* d_ws, size_t ws_size,
                              hipStream_t stream) {
    const float* raw        = (const float*)d_in[0];   // (64, 29)
    const float* forcing    = (const float*)d_in[1];   // (8192, 3)
    const float* state_init = (const float*)d_in[2];   // (2,)
    const float* area_frac  = (const float*)d_in[3];   // (16,)
    const float* mean_elev  = (const float*)d_in[4];   // (16,)

    float* out = (float*)d_out;                        // (64, 8192)

    fuse_pipe_kernel<<<16, 256, 0, stream>>>(raw, forcing, state_init,
                                             area_frac, mean_elev, out);
    route_kernel<<<64, 256, 0, stream>>>(raw, out);
}

// Round 12
// 379.376 us; speedup vs baseline: 1.2389x; 1.2388x over previous
//
#include <hip/hip_runtime.h>
#include <math.h>

#define T_STEPS 8192
#define GROUP   32
#define NG      (T_STEPS / GROUP)   // 256 groups

// hardware transcendentals (v_exp_f32 = 2^x, v_log_f32 = log2 x)
__device__ __forceinline__ float hw_exp2(float x) { return __builtin_amdgcn_exp2f(x); }
__device__ __forceinline__ float hw_log2(float x) { return __builtin_amdgcn_logf(x); }

#if __has_builtin(__builtin_amdgcn_fmed3f)
__device__ __forceinline__ float clamp01(float x) { return __builtin_amdgcn_fmed3f(x, 0.0f, 1.0f); }
#else
__device__ __forceinline__ float clamp01(float x) { return fminf(fmaxf(x, 0.0f), 1.0f); }
#endif

// ---------------------------------------------------------------------------
// 4-wave specialized pipeline, normalized-state recurrences, b128 handoffs.
//   wave0 (A):  snow bucket -> fi' = infl/s1max, fc = 1-(pet+ki)/s1max
//   wave1 (B):  w1 recurrence (chain: log,mul,exp,fma,fma,med3) -> af*perc,
//               af*(qsurf+qif)
//   wave2 (C1): band sums as float4 quad-step adds (lane = {arr,e,quad})
//   wave3 (C2): v2 recurrence (chain: log,mul,exp,fma,med3) -> q
// R10 post-mortem: the s1 chain itself (~130cy/step incl ~30cy trans latency)
// is the floor; this round cuts chain ops (med3-normalized states) and the
// ~900cy/group of serialized b32 LDS issue (b128 packing).
// ---------------------------------------------------------------------------
__global__ __launch_bounds__(256, 1) void fuse_pipe_kernel(
    const float* __restrict__ raw,        // [64][29]
    const float* __restrict__ forcing,    // [8192][3]
    const float* __restrict__ state_init, // [2]
    const float* __restrict__ area_frac,  // [16]
    const float* __restrict__ mean_elev,  // [16]
    float* __restrict__ qout)             // d_out: [64][8192]
{
    const int tid  = threadIdx.x;
    const int wid  = tid >> 6;      // 0..3
    const int lane = tid & 63;
    const int grp  = lane >> 4;     // ensemble within wave
    const int nb   = lane & 15;     // band
    const int e    = blockIdx.x * 4 + grp;

    // A -> B: packed 4 steps per float4, [quad][lane] (b128 both sides, conflict-free)
    __shared__ float4 bufI4[2][8][64];   // infl * inv_s1max
    __shared__ float4 bufC4[2][8][64];   // 1 - (pet+ki)*inv_s1max
    // B -> C1: packed, row padded to 67 float4 for bank spread on C1's reads
    __shared__ float4 bufP4[2][8][67];   // af*perc
    __shared__ float4 bufQ4[2][8][67];   // af*(qsurf+qif)
    // C1 -> C2: per-(e, quad) float4 sums
    __shared__ float4 bufR4[2][4][9];    // rech sums
    __shared__ float4 bufS4[2][4][9];    // surface-q sums

    const float* rp = raw + e * 29;
    auto phys = [&](int idx, float lo, float hi) {
        float x = rp[idx];
        float s = 1.0f / (1.0f + expf(-x));
        return lo + (hi - lo) * s;
    };
    const float s1max = phys(0,  50.0f,  5000.0f);
    const float s2max = phys(1,  100.0f, 10000.0f);
    const float ku    = phys(6,  0.01f,  1000.0f);
    const float c_exp = phys(7,  1.0f,   20.0f);
    const float ki    = phys(11, 0.01f,  1000.0f);
    const float ks    = phys(12, 0.001f, 10000.0f);
    const float n_exp = phys(13, 1.0f,   10.0f);
    const float acmax = phys(17, 0.05f,  0.95f);
    const float b_exp = phys(18, 0.001f, 3.0f);
    const float train = phys(22, -2.0f,  4.0f);
    const float tmelt = phys(23, -2.0f,  4.0f);
    const float mrate = phys(24, 1.0f,   10.0f);
    const float lapse = phys(25, -9.8f,  0.0f);
    const float opg   = phys(26, 0.0f,   1.0f);

    const float delev  = (mean_elev[nb] - 1500.0f) / 1000.0f;
    const float tshift = lapse * delev;
    const float pmult  = fmaxf(1.0f + opg * delev, 0.0f);
    const float af     = area_frac[nb];
    const float inv_s1max = 1.0f / s1max;
    const float inv_s2max = 1.0f / s2max;
    const float kup    = ku * inv_s1max;   // normalized perc coeff
    const float ksn    = ks * inv_s2max;   // normalized baseflow coeff
    const float afku   = af * ku;
    const float afki   = af * ki;
    const float afs1   = af * s1max;

    float swe = 0.0f;
    float w1  = state_init[0] * inv_s1max;   // 50/s1max <= 1 always
    float v2  = state_init[1] * inv_s2max;   // may exceed 1 (g==0 handles)

    float* __restrict__ out = qout + (size_t)e * T_STEPS;
    const float4* __restrict__ fvec = (const float4*)forcing;  // 24 float4/group

    for (int i = 0; i < NG + 3; ++i) {
        if (wid == 0) {
            // ---- stage A: snow bucket + normalized precompute, group i ----
            if (i < NG) {
                const int pb_ = i & 1;
                float f[96];
                const int base = i * 24;
                #pragma unroll
                for (int j = 0; j < 24; ++j) {
                    const float4 L = fvec[base + j];
                    f[4*j+0] = L.x; f[4*j+1] = L.y; f[4*j+2] = L.z; f[4*j+3] = L.w;
                }
                float4 vi, vc;
                #pragma unroll
                for (int tt = 0; tt < GROUP; ++tt) {
                    const float p    = f[3*tt + 0];
                    const float pet  = f[3*tt + 1];
                    const float tair = f[3*tt + 2];
                    const float tb   = tair + tshift;
                    const float pcp  = p * pmult;
                    const float snow = (tb > train) ? 0.0f : pcp;
                    const float ssn  = swe + snow;
                    const float mcap = mrate * fmaxf(tb - tmelt, 0.0f);
                    const float swen = fmaxf(ssn - mcap, 0.0f);
                    const float infl = pcp + swe - swen;        // rain + melt
                    swe = swen;
                    const int c3 = tt & 3;
                    (&vi.x)[c3] = infl * inv_s1max;
                    (&vc.x)[c3] = fmaf(-(pet + ki), inv_s1max, 1.0f);
                    if (c3 == 3) {
                        bufI4[pb_][tt >> 2][lane] = vi;
                        bufC4[pb_][tt >> 2][lane] = vc;
                    }
                }
            }
        } else if (wid == 1) {
            // ---- stage B: w1 recurrence, group i-1 ----
            const int g = i - 1;
            if (g >= 0 && g < NG) {
                const int pb_ = g & 1;
                float4 fi4[8], fc4[8];
                #pragma unroll
                for (int k = 0; k < 8; ++k) {
                    fi4[k] = bufI4[pb_][k][lane];
                    fc4[k] = bufC4[pb_][k][lane];
                }
                #pragma unroll
                for (int k = 0; k < 8; ++k)
                    asm volatile("" : "+v"(fi4[k].x), "+v"(fi4[k].y),
                                      "+v"(fi4[k].z), "+v"(fi4[k].w),
                                      "+v"(fc4[k].x), "+v"(fc4[k].y),
                                      "+v"(fc4[k].z), "+v"(fc4[k].w));

                float4 oP, oQ;
                #pragma unroll
                for (int tt = 0; tt < GROUP; ++tt) {
                    const int k = tt >> 2, c3 = tt & 3;
                    const float fi  = (&fi4[k].x)[c3];
                    const float fcv = (&fc4[k].x)[c3];
                    const float fap = acmax * fi;               // off-chain
                    // chain: log -> mul -> exp -> fma -> fma -> med3
                    const float lg  = hw_log2(w1);              // log2(0)=-inf ok
                    const float pwc = hw_exp2(c_exp * lg);      // w1^c
                    const float pwb = hw_exp2(b_exp * lg);      // w1^b
                    const float u   = fmaf(fcv, w1, fi);        // early, parallel
                    const float u1  = fmaf(-kup, pwc, u);
                    const float u2  = fmaf(-fap, pwb, u1);
                    const float over1 = fmaxf(u2 - 1.0f, 0.0f); // off-chain
                    const float qift  = afki * w1;              // off-chain
                    w1 = clamp01(u2);
                    const float qsxn = fap * pwb;               // normalized qsx
                    (&oP.x)[c3] = afku * pwc;                   // af*perc
                    (&oQ.x)[c3] = fmaf(afs1, qsxn + over1, qift);
                    if (c3 == 3) {
                        bufP4[pb_][k][lane] = oP;
                        bufQ4[pb_][k][lane] = oQ;
                    }
                }
            }
        } else if (wid == 2) {
            // ---- stage C1: band sums (float4 quad-step adds), group i-2 ----
            const int g = i - 2;
            if (g >= 0 && g < NG) {
                const int pb_ = g & 1;
                const int arr = lane >> 5;        // 0: P(rech), 1: Q(surface)
                const int se  = (lane >> 3) & 3;  // ensemble
                const int tq  = lane & 7;         // quad-step (4 steps)
                const float4* src = arr ? &bufQ4[pb_][tq][se * 16]
                                        : &bufP4[pb_][tq][se * 16];
                float4 s = src[0];
                #pragma unroll
                for (int n = 1; n < 16; ++n) {
                    const float4 v = src[n];
                    s.x += v.x; s.y += v.y; s.z += v.z; s.w += v.w;
                }
                if (arr) bufS4[pb_][se][tq] = s;
                else     bufR4[pb_][se][tq] = s;
            }
        } else {
            // ---- stage C2: v2 recurrence + q, group i-3 ----
            const int g = i - 3;
            if (g >= 0) {
                const int pb_ = g & 1;
                float4 r4[8], s4[8];
                #pragma unroll
                for (int k = 0; k < 8; ++k) {
                    r4[k] = bufR4[pb_][grp][k];   // broadcast reads
                    s4[k] = bufS4[pb_][grp][k];
                }
                #pragma unroll
                for (int k = 0; k < 8; ++k)
                    asm volatile("" : "+v"(r4[k].x), "+v"(r4[k].y),
                                      "+v"(r4[k].z), "+v"(r4[k].w),
                                      "+v"(s4[k].x), "+v"(s4[k].y),
                                      "+v"(s4[k].z), "+v"(s4[k].w));

                float qk0 = 0.0f, qk1 = 0.0f;
                auto c2body = [&](bool clampPw) {
                    #pragma unroll
                    for (int tt = 0; tt < GROUP; ++tt) {
                        const float rech = (&r4[tt >> 2].x)[tt & 3];
                        const float qsum = (&s4[tt >> 2].x)[tt & 3];
                        // chain: log -> mul(+min) -> exp -> fma -> med3
                        const float lg2 = hw_log2(v2);
                        float m = n_exp * lg2;
                        if (clampPw) m = fminf(m, 0.0f);  // only while v2 may be >1
                        const float pwm = hw_exp2(m);     // clip(w2)^n
                        const float u   = fmaf(rech, inv_s2max, v2);  // early
                        const float u2  = fmaf(-ksn, pwm, u);
                        const float over2 = fmaxf(u2 - 1.0f, 0.0f);   // off-chain
                        v2 = clamp01(u2);
                        const float q = fmaf(s2max, over2, fmaf(ks, pwm, qsum));
                        if (tt < 16) qk0 = (tt == nb) ? q : qk0;
                        else         qk1 = ((tt - 16) == nb) ? q : qk1;
                    }
                };
                if (g == 0) c2body(true); else c2body(false);

                float* __restrict__ o = out + g * GROUP;
                o[nb]      = qk0;
                o[nb + 16] = qk1;
            }
        }
        __syncthreads();
    }
}

// ---------------------------------------------------------------------------
// Route: gamma unit-hydrograph, 30-tap causal FIR along time. In-place on
// d_out (full row staged in LDS before any write).
// ---------------------------------------------------------------------------
__global__ __launch_bounds__(256) void route_kernel(
    const float* __restrict__ raw,     // [64][29]
    float* __restrict__ q_io)          // d_out: in = q, out = routed
{
    __shared__ float w_sh[32];
    __shared__ float row[T_STEPS];     // 32 KB

    const int e   = blockIdx.x;
    const int tid = threadIdx.x;

    const float4* src  = (const float4*)(q_io + (size_t)e * T_STEPS);
    float4*       dst4 = (float4*)row;
    for (int i = tid; i < T_STEPS / 4; i += 256) dst4[i] = src[i];

    if (tid < 32) {
        float x     = raw[e * 29 + 21];                 // mu_t raw
        float sig   = 1.0f / (1.0f + expf(-x));
        float delay = 0.01f + (5.0f - 0.01f) * sig;
        float wv = 0.0f;
        if (tid < 30) {
            const float tm   = (float)tid + 0.5f;
            const float kk   = 2.5f;
            const float lgam = 0.28468287047291918f;    // lgamma(2.5)
            float lp = (kk - 1.0f) * logf(tm) - tm / delay - lgam - kk * logf(delay);
            wv = expf(lp);
        }
        w_sh[tid] = wv;
    }
    __syncthreads();
    if (tid == 0) {
        float s = 0.0f;
        for (int l = 0; l < 30; ++l) s += w_sh[l];
        w_sh[31] = 1.0f / s;
    }
    __syncthreads();

    float wloc[30];
    const float inv = w_sh[31];
    #pragma unroll
    for (int l = 0; l < 30; ++l) wloc[l] = w_sh[l] * inv;

    float* __restrict__ out = q_io + (size_t)e * T_STEPS;
    for (int t = tid; t < T_STEPS; t += 256) {
        float acc = 0.0f;
        #pragma unroll
        for (int l = 0; l < 30; ++l) {
            const int idx = t - l;
            const float v = (idx >= 0) ? row[idx] : 0.0f;
            acc = fmaf(wloc[l], v, acc);
        }
        out[t] = acc;
    }
}

// ---------------------------------------------------------------------------
extern "C" void kernel_launch(void* const* d_in, const int* in_sizes, int n_in,
                              void* d_out, int out_size, void* d_ws, size_t ws_size,
                              hipStream_t stream) {
    const float* raw        = (const float*)d_in[0];   // (64, 29)
    const float* forcing    = (const float*)d_in[1];   // (8192, 3)
    const float* state_init = (const float*)d_in[2];   // (2,)
    const float* area_frac  = (const float*)d_in[3];   // (16,)
    const float* mean_elev  = (const float*)d_in[4];   // (16,)

    float* out = (float*)d_out;                        // (64, 8192)

    fuse_pipe_kernel<<<16, 256, 0, stream>>>(raw, forcing, state_init,
                                             area_frac, mean_elev, out);
    route_kernel<<<64, 256, 0, stream>>>(raw, out);
}

// Round 13
// 360.738 us; speedup vs baseline: 1.3029x; 1.0517x over previous
//
#include <hip/hip_runtime.h>
#include <math.h>

#define T_STEPS 8192
#define GROUP   64
#define NQ      (GROUP / 4)          // 16 quads per group
#define NG      (T_STEPS / GROUP)    // 128 groups

// hardware transcendentals (v_exp_f32 = 2^x, v_log_f32 = log2 x)
__device__ __forceinline__ float hw_exp2(float x) { return __builtin_amdgcn_exp2f(x); }
__device__ __forceinline__ float hw_log2(float x) { return __builtin_amdgcn_logf(x); }

#if __has_builtin(__builtin_amdgcn_fmed3f)
__device__ __forceinline__ float clamp01(float x) { return __builtin_amdgcn_fmed3f(x, 0.0f, 1.0f); }
#else
__device__ __forceinline__ float clamp01(float x) { return fminf(fmaxf(x, 0.0f), 1.0f); }
#endif

// ---------------------------------------------------------------------------
// 4-wave specialized pipeline, GROUP=64, streaming LDS heads.
//   wave0 (A):  snow bucket -> infl/s1max, 1-(pet+ki)/s1max   (4x12-float4 chunks)
//   wave1 (B):  w1 recurrence -> af*perc, af*(qsurf+qif)      [chain ~76cy/step]
//   wave2 (C1): band sums as float4 quad-step adds
//   wave3 (C2): v2 recurrence -> q
// R11 post-mortem: ~25-30cy/step of per-group fixed cost (pinned LDS heads,
// barriers) on the critical wave. GROUP=64 halves it; per-quad streaming
// reads (no pin-all) expose only the first read's latency per group.
// ---------------------------------------------------------------------------
__global__ __launch_bounds__(256, 1) void fuse_pipe_kernel(
    const float* __restrict__ raw,        // [64][29]
    const float* __restrict__ forcing,    // [8192][3]
    const float* __restrict__ state_init, // [2]
    const float* __restrict__ area_frac,  // [16]
    const float* __restrict__ mean_elev,  // [16]
    float* __restrict__ qout)             // d_out: [64][8192]
{
    const int tid  = threadIdx.x;
    const int wid  = tid >> 6;      // 0..3
    const int lane = tid & 63;
    const int grp  = lane >> 4;     // ensemble within wave
    const int nb   = lane & 15;     // band
    const int e    = blockIdx.x * 4 + grp;

    // A -> B: packed 4 steps per float4, [quad][lane]
    __shared__ float4 bufI4[2][NQ][64];   // infl * inv_s1max
    __shared__ float4 bufC4[2][NQ][64];   // 1 - (pet+ki)*inv_s1max
    // B -> C1: row padded to 67 float4
    __shared__ float4 bufP4[2][NQ][67];   // af*perc
    __shared__ float4 bufQ4[2][NQ][67];   // af*(qsurf+qif)
    // C1 -> C2: per-(e, quad) sums, row padded to NQ+1
    __shared__ float4 bufR4[2][4][NQ + 1];   // rech sums
    __shared__ float4 bufS4[2][4][NQ + 1];   // surface-q sums
    // total approx 138 KB

    const float* rp = raw + e * 29;
    auto phys = [&](int idx, float lo, float hi) {
        float x = rp[idx];
        float s = 1.0f / (1.0f + expf(-x));
        return lo + (hi - lo) * s;
    };
    const float s1max = phys(0,  50.0f,  5000.0f);
    const float s2max = phys(1,  100.0f, 10000.0f);
    const float ku    = phys(6,  0.01f,  1000.0f);
    const float c_exp = phys(7,  1.0f,   20.0f);
    const float ki    = phys(11, 0.01f,  1000.0f);
    const float ks    = phys(12, 0.001f, 10000.0f);
    const float n_exp = phys(13, 1.0f,   10.0f);
    const float acmax = phys(17, 0.05f,  0.95f);
    const float b_exp = phys(18, 0.001f, 3.0f);
    const float train = phys(22, -2.0f,  4.0f);
    const float tmelt = phys(23, -2.0f,  4.0f);
    const float mrate = phys(24, 1.0f,   10.0f);
    const float lapse = phys(25, -9.8f,  0.0f);
    const float opg   = phys(26, 0.0f,   1.0f);

    const float delev  = (mean_elev[nb] - 1500.0f) / 1000.0f;
    const float tshift = lapse * delev;
    const float pmult  = fmaxf(1.0f + opg * delev, 0.0f);
    const float af     = area_frac[nb];
    const float inv_s1max = 1.0f / s1max;
    const float inv_s2max = 1.0f / s2max;
    const float kup    = ku * inv_s1max;   // normalized perc coeff
    const float ksn    = ks * inv_s2max;   // normalized baseflow coeff
    const float afku   = af * ku;
    const float afki   = af * ki;
    const float afs1   = af * s1max;

    float swe = 0.0f;
    float w1  = state_init[0] * inv_s1max;   // <= 1 always
    float v2  = state_init[1] * inv_s2max;   // may exceed 1 (g==0 handles)

    float* __restrict__ out = qout + (size_t)e * T_STEPS;
    const float4* __restrict__ fvec = (const float4*)forcing;  // 48 float4/group

    for (int i = 0; i < NG + 3; ++i) {
        if (wid == 0) {
            // ---- stage A: snow bucket + normalized precompute, group i ----
            if (i < NG) {
                const int pb_ = i & 1;
                const int base = i * 48;
                #pragma unroll
                for (int h = 0; h < 4; ++h) {          // 4 chunks x 16 steps
                    float f[48];
                    #pragma unroll
                    for (int j = 0; j < 12; ++j) {
                        const float4 L = fvec[base + h * 12 + j];
                        f[4*j+0] = L.x; f[4*j+1] = L.y; f[4*j+2] = L.z; f[4*j+3] = L.w;
                    }
                    float4 vi, vc;
                    #pragma unroll
                    for (int s = 0; s < 16; ++s) {
                        const int tt = h * 16 + s;
                        const float p    = f[3*s + 0];
                        const float pet  = f[3*s + 1];
                        const float tair = f[3*s + 2];
                        const float tb   = tair + tshift;
                        const float pcp  = p * pmult;
                        const float snow = (tb > train) ? 0.0f : pcp;
                        const float ssn  = swe + snow;
                        const float mcap = mrate * fmaxf(tb - tmelt, 0.0f);
                        const float swen = fmaxf(ssn - mcap, 0.0f);
                        const float infl = pcp + swe - swen;    // rain + melt
                        swe = swen;
                        const int c3 = tt & 3;
                        (&vi.x)[c3] = infl * inv_s1max;
                        (&vc.x)[c3] = fmaf(-(pet + ki), inv_s1max, 1.0f);
                        if (c3 == 3) {
                            bufI4[pb_][tt >> 2][lane] = vi;
                            bufC4[pb_][tt >> 2][lane] = vc;
                        }
                    }
                }
            }
        } else if (wid == 1) {
            // ---- stage B: w1 recurrence, group i-1 (streaming reads) ----
            const int g = i - 1;
            if (g >= 0 && g < NG) {
                const int pb_ = g & 1;
                #pragma unroll
                for (int k = 0; k < NQ; ++k) {
                    const float4 fi4 = bufI4[pb_][k][lane];
                    const float4 fc4 = bufC4[pb_][k][lane];
                    float4 oP, oQ;
                    #pragma unroll
                    for (int c3 = 0; c3 < 4; ++c3) {
                        const float fi  = (&fi4.x)[c3];
                        const float fcv = (&fc4.x)[c3];
                        const float fap = acmax * fi;               // off-chain
                        // chain: log -> mul -> exp -> fma -> fma -> med3
                        const float lg  = hw_log2(w1);              // log2(0)=-inf ok
                        const float pwc = hw_exp2(c_exp * lg);      // w1^c
                        const float pwb = hw_exp2(b_exp * lg);      // w1^b
                        const float u   = fmaf(fcv, w1, fi);        // parallel arm
                        const float u1  = fmaf(-kup, pwc, u);
                        const float u2  = fmaf(-fap, pwb, u1);
                        const float over1 = fmaxf(u2 - 1.0f, 0.0f); // off-chain
                        const float qift  = afki * w1;              // off-chain
                        w1 = clamp01(u2);
                        const float qsxn = fap * pwb;
                        (&oP.x)[c3] = afku * pwc;                   // af*perc
                        (&oQ.x)[c3] = fmaf(afs1, qsxn + over1, qift);
                    }
                    bufP4[pb_][k][lane] = oP;
                    bufQ4[pb_][k][lane] = oQ;
                }
            }
        } else if (wid == 2) {
            // ---- stage C1: band sums (float4 quad-step adds), group i-2 ----
            const int g = i - 2;
            if (g >= 0 && g < NG) {
                const int pb_ = g & 1;
                const int arr = lane >> 5;        // 0: P(rech), 1: Q(surface)
                const int se  = (lane >> 3) & 3;  // ensemble
                const int tq  = lane & 7;         // quad-step base
                #pragma unroll
                for (int j = 0; j < 2; ++j) {
                    const int q_ = tq + 8 * j;
                    const float4* src = arr ? &bufQ4[pb_][q_][se * 16]
                                            : &bufP4[pb_][q_][se * 16];
                    float4 s = src[0];
                    #pragma unroll
                    for (int n = 1; n < 16; ++n) {
                        const float4 v = src[n];
                        s.x += v.x; s.y += v.y; s.z += v.z; s.w += v.w;
                    }
                    if (arr) bufS4[pb_][se][q_] = s;
                    else     bufR4[pb_][se][q_] = s;
                }
            }
        } else {
            // ---- stage C2: v2 recurrence + q, group i-3 (streaming reads) ----
            const int g = i - 3;
            if (g >= 0) {
                const int pb_ = g & 1;
                float qk0 = 0.0f, qk1 = 0.0f, qk2 = 0.0f, qk3 = 0.0f;
                auto c2body = [&](bool clampPw) {
                    #pragma unroll
                    for (int k = 0; k < NQ; ++k) {
                        const float4 r4 = bufR4[pb_][grp][k];   // broadcast
                        const float4 s4 = bufS4[pb_][grp][k];
                        #pragma unroll
                        for (int c3 = 0; c3 < 4; ++c3) {
                            const int tt = 4 * k + c3;
                            const float rech = (&r4.x)[c3];
                            const float qsum = (&s4.x)[c3];
                            // chain: log -> mul(+min) -> exp -> fma -> med3
                            const float lg2 = hw_log2(v2);
                            float m = n_exp * lg2;
                            if (clampPw) m = fminf(m, 0.0f);  // only while v2>1 possible
                            const float pwm = hw_exp2(m);     // clip(w2)^n
                            const float u   = fmaf(rech, inv_s2max, v2);
                            const float u2  = fmaf(-ksn, pwm, u);
                            const float over2 = fmaxf(u2 - 1.0f, 0.0f);
                            v2 = clamp01(u2);
                            const float q = fmaf(s2max, over2, fmaf(ks, pwm, qsum));
                            const bool sel = (tt & 15) == nb;
                            if      (tt < 16) qk0 = sel ? q : qk0;
                            else if (tt < 32) qk1 = sel ? q : qk1;
                            else if (tt < 48) qk2 = sel ? q : qk2;
                            else              qk3 = sel ? q : qk3;
                        }
                    }
                };
                if (g == 0) c2body(true); else c2body(false);

                float* __restrict__ o = out + g * GROUP;
                o[nb]      = qk0;
                o[nb + 16] = qk1;
                o[nb + 32] = qk2;
                o[nb + 48] = qk3;
            }
        }
        __syncthreads();
    }
}

// ---------------------------------------------------------------------------
// Route: gamma unit-hydrograph, 30-tap causal FIR along time. In-place on
// d_out (full row staged in LDS before any write).
// ---------------------------------------------------------------------------
__global__ __launch_bounds__(256) void route_kernel(
    const float* __restrict__ raw,     // [64][29]
    float* __restrict__ q_io)          // d_out: in = q, out = routed
{
    __shared__ float w_sh[32];
    __shared__ float row[T_STEPS];     // 32 KB

    const int e   = blockIdx.x;
    const int tid = threadIdx.x;

    const float4* src  = (const float4*)(q_io + (size_t)e * T_STEPS);
    float4*       dst4 = (float4*)row;
    for (int i = tid; i < T_STEPS / 4; i += 256) dst4[i] = src[i];

    if (tid < 32) {
        float x     = raw[e * 29 + 21];                 // mu_t raw
        float sig   = 1.0f / (1.0f + expf(-x));
        float delay = 0.01f + (5.0f - 0.01f) * sig;
        float wv = 0.0f;
        if (tid < 30) {
            const float tm   = (float)tid + 0.5f;
            const float kk   = 2.5f;
            const float lgam = 0.28468287047291918f;    // lgamma(2.5)
            float lp = (kk - 1.0f) * logf(tm) - tm / delay - lgam - kk * logf(delay);
            wv = expf(lp);
        }
        w_sh[tid] = wv;
    }
    __syncthreads();
    if (tid == 0) {
        float s = 0.0f;
        for (int l = 0; l < 30; ++l) s += w_sh[l];
        w_sh[31] = 1.0f / s;
    }
    __syncthreads();

    float wloc[30];
    const float inv = w_sh[31];
    #pragma unroll
    for (int l = 0; l < 30; ++l) wloc[l] = w_sh[l] * inv;

    float* __restrict__ out = q_io + (size_t)e * T_STEPS;
    for (int t = tid; t < T_STEPS; t += 256) {
        float acc = 0.0f;
        #pragma unroll
        for (int l = 0; l < 30; ++l) {
            const int idx = t - l;
            const float v = (idx >= 0) ? row[idx] : 0.0f;
            acc = fmaf(wloc[l], v, acc);
        }
        out[t] = acc;
    }
}

// ---------------------------------------------------------------------------
extern "C" void kernel_launch(void* const* d_in, const int* in_sizes, int n_in,
                              void* d_out, int out_size, void* d_ws, size_t ws_size,
                              hipStream_t stream) {
    const float* raw        = (const float*)d_in[0];   // (64, 29)
    const float* forcing    = (const float*)d_in[1];   // (8192, 3)
    const float* state_init = (const float*)d_in[2];   // (2,)
    const float* area_frac  = (const float*)d_in[3];   // (16,)
    const float* mean_elev  = (const float*)d_in[4];   // (16,)

    float* out = (float*)d_out;                        // (64, 8192)

    fuse_pipe_kernel<<<16, 256, 0, stream>>>(raw, forcing, state_init,
                                             area_frac, mean_elev, out);
    route_kernel<<<64, 256, 0, stream>>>(raw, out);
}

// Round 14
// 339.949 us; speedup vs baseline: 1.3826x; 1.0612x over previous
//
#include <hip/hip_runtime.h>
#include <math.h>

#define T_STEPS 8192
#define GROUP   64
#define NQ      (GROUP / 4)          // 16 quads per group
#define NG      (T_STEPS / GROUP)    // 128 groups
#define UH      30

// hardware transcendentals (v_exp_f32 = 2^x, v_log_f32 = log2 x)
__device__ __forceinline__ float hw_exp2(float x) { return __builtin_amdgcn_exp2f(x); }
__device__ __forceinline__ float hw_log2(float x) { return __builtin_amdgcn_logf(x); }

#if __has_builtin(__builtin_amdgcn_fmed3f)
__device__ __forceinline__ float clamp01(float x) { return __builtin_amdgcn_fmed3f(x, 0.0f, 1.0f); }
#else
__device__ __forceinline__ float clamp01(float x) { return fminf(fmaxf(x, 0.0f), 1.0f); }
#endif

// ---------------------------------------------------------------------------
// 5-wave specialized pipeline, GROUP=64. 16 blocks x 320 threads.
//   wave0 (A):  snow bucket -> infl/s1max, 1-(pet+ki)/s1max      [lag 0]
//   wave1 (B):  w1 recurrence -> af*perc, af*(qsurf+qif)         [lag 1]
//   wave2 (C1): band sums (float4 quad adds)                     [lag 2]
//   wave3 (C2): v2 recurrence -> q into LDS ring                 [lag 3]
//   wave4 (R):  30-tap gamma-UH FIR from ring -> routed (global) [lag 5]
// R shares SIMD0 with A (both slack). Ring has 4 slots of 64 q's per
// ensemble: writer slot (g+2)%4 vs reader slots g%4,(g+3)%4 -> no race.
// Route kernel is GONE: its ~15-20us tail now hides under the pipeline.
// ---------------------------------------------------------------------------
__global__ __launch_bounds__(320, 1) void fuse_pipe_kernel(
    const float* __restrict__ raw,        // [64][29]
    const float* __restrict__ forcing,    // [8192][3]
    const float* __restrict__ state_init, // [2]
    const float* __restrict__ area_frac,  // [16]
    const float* __restrict__ mean_elev,  // [16]
    float* __restrict__ routed)           // d_out: [64][8192]
{
    const int tid  = threadIdx.x;
    const int wid  = tid >> 6;      // 0..4
    const int lane = tid & 63;
    const int grp  = lane >> 4;     // ensemble within wave
    const int nb   = lane & 15;     // band
    const int e    = blockIdx.x * 4 + grp;

    // A -> B: packed 4 steps per float4, [quad][lane]
    __shared__ float4 bufI4[2][NQ][64];   // infl * inv_s1max
    __shared__ float4 bufC4[2][NQ][64];   // 1 - (pet+ki)*inv_s1max
    // B -> C1: row padded to 67 float4
    __shared__ float4 bufP4[2][NQ][67];   // af*perc
    __shared__ float4 bufQ4[2][NQ][67];   // af*(qsurf+qif)
    // C1 -> C2: per-(e, quad) sums
    __shared__ float4 bufR4[2][4][NQ + 1];   // rech sums
    __shared__ float4 bufS4[2][4][NQ + 1];   // surface-q sums
    // C2 -> R: q ring, 4 slots x 64 steps per ensemble (row padded to 257)
    __shared__ float qring[4][257];

    // zero-init ring (R's negative-time taps at g=0 read slot 3 = zeros)
    for (int k = tid; k < 4 * 257; k += 320)
        ((float*)qring)[k] = 0.0f;

    const float* rp = raw + e * 29;
    auto phys = [&](int idx, float lo, float hi) {
        float x = rp[idx];
        float s = 1.0f / (1.0f + expf(-x));
        return lo + (hi - lo) * s;
    };
    const float s1max = phys(0,  50.0f,  5000.0f);
    const float s2max = phys(1,  100.0f, 10000.0f);
    const float ku    = phys(6,  0.01f,  1000.0f);
    const float c_exp = phys(7,  1.0f,   20.0f);
    const float ki    = phys(11, 0.01f,  1000.0f);
    const float ks    = phys(12, 0.001f, 10000.0f);
    const float n_exp = phys(13, 1.0f,   10.0f);
    const float acmax = phys(17, 0.05f,  0.95f);
    const float b_exp = phys(18, 0.001f, 3.0f);
    const float train = phys(22, -2.0f,  4.0f);
    const float tmelt = phys(23, -2.0f,  4.0f);
    const float mrate = phys(24, 1.0f,   10.0f);
    const float lapse = phys(25, -9.8f,  0.0f);
    const float opg   = phys(26, 0.0f,   1.0f);

    const float delev  = (mean_elev[nb] - 1500.0f) / 1000.0f;
    const float tshift = lapse * delev;
    const float pmult  = fmaxf(1.0f + opg * delev, 0.0f);
    const float af     = area_frac[nb];
    const float inv_s1max = 1.0f / s1max;
    const float inv_s2max = 1.0f / s2max;
    const float kup    = ku * inv_s1max;
    const float ksn    = ks * inv_s2max;
    const float afku   = af * ku;
    const float afki   = af * ki;
    const float afs1   = af * s1max;

    float swe = 0.0f;
    float w1  = state_init[0] * inv_s1max;   // <= 1 always
    float v2  = state_init[1] * inv_s2max;   // may exceed 1 (g==0 handles)

    // gamma-UH weights for wave R (static tap indices -> registers)
    float wloc[UH];
    if (wid == 4) {
        const float x     = raw[e * 29 + 21];            // mu_t raw
        const float sig   = 1.0f / (1.0f + expf(-x));
        const float delay = 0.01f + (5.0f - 0.01f) * sig;
        const float lgd   = logf(delay);
        const float invd  = 1.0f / delay;
        float s = 0.0f;
        #pragma unroll
        for (int l = 0; l < UH; ++l) {
            const float tm = (float)l + 0.5f;
            const float lp = 1.5f * logf(tm) - tm * invd
                           - 0.28468287047291918f - 2.5f * lgd;
            wloc[l] = expf(lp);
            s += wloc[l];
        }
        const float inv = 1.0f / s;
        #pragma unroll
        for (int l = 0; l < UH; ++l) wloc[l] *= inv;
    }

    float* __restrict__ out = routed + (size_t)e * T_STEPS;
    const float4* __restrict__ fvec = (const float4*)forcing;  // 48 float4/group

    for (int i = 0; i < NG + 5; ++i) {
        if (wid == 0) {
            // ---- stage A: snow bucket + normalized precompute, group i ----
            if (i < NG) {
                const int pb_ = i & 1;
                const int base = i * 48;
                #pragma unroll
                for (int h = 0; h < 4; ++h) {          // 4 chunks x 16 steps
                    float f[48];
                    #pragma unroll
                    for (int j = 0; j < 12; ++j) {
                        const float4 L = fvec[base + h * 12 + j];
                        f[4*j+0] = L.x; f[4*j+1] = L.y; f[4*j+2] = L.z; f[4*j+3] = L.w;
                    }
                    float4 vi, vc;
                    #pragma unroll
                    for (int s = 0; s < 16; ++s) {
                        const int tt = h * 16 + s;
                        const float p    = f[3*s + 0];
                        const float pet  = f[3*s + 1];
                        const float tair = f[3*s + 2];
                        const float tb   = tair + tshift;
                        const float pcp  = p * pmult;
                        const float snow = (tb > train) ? 0.0f : pcp;
                        const float ssn  = swe + snow;
                        const float mcap = mrate * fmaxf(tb - tmelt, 0.0f);
                        const float swen = fmaxf(ssn - mcap, 0.0f);
                        const float infl = pcp + swe - swen;    // rain + melt
                        swe = swen;
                        const int c3 = tt & 3;
                        (&vi.x)[c3] = infl * inv_s1max;
                        (&vc.x)[c3] = fmaf(-(pet + ki), inv_s1max, 1.0f);
                        if (c3 == 3) {
                            bufI4[pb_][tt >> 2][lane] = vi;
                            bufC4[pb_][tt >> 2][lane] = vc;
                        }
                    }
                }
            }
        } else if (wid == 1) {
            // ---- stage B: w1 recurrence, group i-1 (hoisted reads, no pins) ----
            const int g = i - 1;
            if (g >= 0 && g < NG) {
                const int pb_ = g & 1;
                float4 fi4[NQ], fc4[NQ];
                #pragma unroll
                for (int k = 0; k < NQ; ++k) {
                    fi4[k] = bufI4[pb_][k][lane];
                    fc4[k] = bufC4[pb_][k][lane];
                }
                #pragma unroll
                for (int k = 0; k < NQ; ++k) {
                    float4 oP, oQ;
                    #pragma unroll
                    for (int c3 = 0; c3 < 4; ++c3) {
                        const float fi  = (&fi4[k].x)[c3];
                        const float fcv = (&fc4[k].x)[c3];
                        const float fap = acmax * fi;               // off-chain
                        // chain: log -> mul -> exp -> fma -> fma -> med3
                        const float lg  = hw_log2(w1);              // log2(0)=-inf ok
                        const float pwc = hw_exp2(c_exp * lg);      // w1^c
                        const float pwb = hw_exp2(b_exp * lg);      // w1^b
                        const float u   = fmaf(fcv, w1, fi);        // parallel arm
                        const float u1  = fmaf(-kup, pwc, u);
                        const float u2  = fmaf(-fap, pwb, u1);
                        const float over1 = fmaxf(u2 - 1.0f, 0.0f); // off-chain
                        const float qift  = afki * w1;              // off-chain
                        w1 = clamp01(u2);
                        const float qsxn = fap * pwb;
                        (&oP.x)[c3] = afku * pwc;                   // af*perc
                        (&oQ.x)[c3] = fmaf(afs1, qsxn + over1, qift);
                    }
                    bufP4[pb_][k][lane] = oP;
                    bufQ4[pb_][k][lane] = oQ;
                }
            }
        } else if (wid == 2) {
            // ---- stage C1: band sums (float4 quad-step adds), group i-2 ----
            const int g = i - 2;
            if (g >= 0 && g < NG) {
                const int pb_ = g & 1;
                const int arr = lane >> 5;        // 0: P(rech), 1: Q(surface)
                const int se  = (lane >> 3) & 3;  // ensemble
                const int tq  = lane & 7;         // quad-step base
                #pragma unroll
                for (int j = 0; j < 2; ++j) {
                    const int q_ = tq + 8 * j;
                    const float4* src = arr ? &bufQ4[pb_][q_][se * 16]
                                            : &bufP4[pb_][q_][se * 16];
                    float4 s = src[0];
                    #pragma unroll
                    for (int n = 1; n < 16; ++n) {
                        const float4 v = src[n];
                        s.x += v.x; s.y += v.y; s.z += v.z; s.w += v.w;
                    }
                    if (arr) bufS4[pb_][se][q_] = s;
                    else     bufR4[pb_][se][q_] = s;
                }
            }
        } else if (wid == 3) {
            // ---- stage C2: v2 recurrence, group i-3 -> q into ring ----
            const int g = i - 3;
            if (g >= 0 && g < NG) {
                const int pb_ = g & 1;
                const int slot = (g & 3) * 64;
                float qk0 = 0.0f, qk1 = 0.0f, qk2 = 0.0f, qk3 = 0.0f;
                auto c2body = [&](bool clampPw) {
                    #pragma unroll
                    for (int k = 0; k < NQ; ++k) {
                        const float4 r4 = bufR4[pb_][grp][k];   // broadcast
                        const float4 s4 = bufS4[pb_][grp][k];
                        #pragma unroll
                        for (int c3 = 0; c3 < 4; ++c3) {
                            const int tt = 4 * k + c3;
                            const float rech = (&r4.x)[c3];
                            const float qsum = (&s4.x)[c3];
                            // chain: log -> mul(+min) -> exp -> fma -> med3
                            const float lg2 = hw_log2(v2);
                            float m = n_exp * lg2;
                            if (clampPw) m = fminf(m, 0.0f);
                            const float pwm = hw_exp2(m);     // clip(w2)^n
                            const float u   = fmaf(rech, inv_s2max, v2);
                            const float u2  = fmaf(-ksn, pwm, u);
                            const float over2 = fmaxf(u2 - 1.0f, 0.0f);
                            v2 = clamp01(u2);
                            const float q = fmaf(s2max, over2, fmaf(ks, pwm, qsum));
                            const bool sel = (tt & 15) == nb;
                            if      (tt < 16) qk0 = sel ? q : qk0;
                            else if (tt < 32) qk1 = sel ? q : qk1;
                            else if (tt < 48) qk2 = sel ? q : qk2;
                            else              qk3 = sel ? q : qk3;
                        }
                    }
                };
                if (g == 0) c2body(true); else c2body(false);

                qring[grp][slot + nb]      = qk0;
                qring[grp][slot + nb + 16] = qk1;
                qring[grp][slot + nb + 32] = qk2;
                qring[grp][slot + nb + 48] = qk3;
            }
        } else {
            // ---- stage R: gamma-UH FIR, group i-5 -> routed (global) ----
            const int g = i - 5;
            if (g >= 0 && g < NG) {
                const int base = (g & 3) * 64;
                #pragma unroll
                for (int j = 0; j < 4; ++j) {
                    const int pl = nb + 16 * j;           // 0..63
                    float acc = 0.0f;
                    #pragma unroll
                    for (int l = 0; l < UH; ++l) {
                        const int idx = (base + pl - l) & 255;
                        acc = fmaf(wloc[l], qring[grp][idx], acc);
                    }
                    out[g * GROUP + pl] = acc;
                }
            }
        }
        __syncthreads();
    }
}

// ---------------------------------------------------------------------------
extern "C" void kernel_launch(void* const* d_in, const int* in_sizes, int n_in,
                              void* d_out, int out_size, void* d_ws, size_t ws_size,
                              hipStream_t stream) {
    const float* raw        = (const float*)d_in[0];   // (64, 29)
    const float* forcing    = (const float*)d_in[1];   // (8192, 3)
    const float* state_init = (const float*)d_in[2];   // (2,)
    const float* area_frac  = (const float*)d_in[3];   // (16,)
    const float* mean_elev  = (const float*)d_in[4];   // (16,)

    float* out = (float*)d_out;                        // (64, 8192) routed

    fuse_pipe_kernel<<<16, 320, 0, stream>>>(raw, forcing, state_init,
                                             area_frac, mean_elev, out);
}